// Round 1
// baseline (196.707 us; speedup 1.0000x reference)
//
#include <hip/hip_runtime.h>
#include <hip/hip_bf16.h>

#define HID 1024
#define RANK 16
#define NSEG 64

__global__ __launch_bounds__(256) void lora_seg_kernel(
    const float* __restrict__ x,      // [N, H]
    const int*   __restrict__ seg,    // [N]
    const float* __restrict__ A,      // [S, H, R]
    const float* __restrict__ B,      // [S, R, H]
    const float* __restrict__ bias,   // [S, H]
    float*       __restrict__ out)    // [N, H]
{
    const int n    = blockIdx.x;
    const int tid  = threadIdx.x;
    const int lane = tid & 63;
    const int wave = tid >> 6;
    const int s    = seg[n];

    __shared__ float inter_s[RANK];

    // ---- Phase 1: inter[r] = sum_h B[s][r][h] * x[n][h] ----
    // wave w handles r = 4w .. 4w+3 ; lane covers h = lane*16 .. lane*16+15
    const float4* x4 = (const float4*)(x + (size_t)n * HID);
    float4 xv[4];
    #pragma unroll
    for (int k = 0; k < 4; ++k) xv[k] = x4[lane * 4 + k];

    const float4* B4 = (const float4*)(B + (size_t)s * RANK * HID);
    float p[4];
    #pragma unroll
    for (int rr = 0; rr < 4; ++rr) {
        const int r = wave * 4 + rr;
        const float4* Br = B4 + (size_t)r * (HID / 4);
        float acc = 0.f;
        #pragma unroll
        for (int k = 0; k < 4; ++k) {
            float4 b = Br[lane * 4 + k];
            acc += b.x * xv[k].x + b.y * xv[k].y + b.z * xv[k].z + b.w * xv[k].w;
        }
        p[rr] = acc;
    }
    // butterfly reduce each p[rr] across the 64-lane wave
    #pragma unroll
    for (int rr = 0; rr < 4; ++rr) {
        float v = p[rr];
        #pragma unroll
        for (int off = 32; off >= 1; off >>= 1)
            v += __shfl_xor(v, off, 64);
        if (lane == 0) inter_s[wave * 4 + rr] = v;
    }
    __syncthreads();

    float inter[RANK];
    #pragma unroll
    for (int r = 0; r < RANK; ++r) inter[r] = inter_s[r];  // broadcast reads

    // ---- Phase 2: out[n][h] = sum_r A[s][h][r] * inter[r] + bias[s][h] ----
    // thread handles h = 4*tid .. 4*tid+3 ; A row h = 16 contiguous floats
    const float4* A4 = (const float4*)(A + (size_t)s * HID * RANK);
    const float4* b4 = (const float4*)(bias + (size_t)s * HID);
    float4 o = b4[tid];
    float* op = (float*)&o;
    #pragma unroll
    for (int j = 0; j < 4; ++j) {
        const int h = tid * 4 + j;
        const float4* Ah = A4 + (size_t)h * (RANK / 4);
        float acc = 0.f;
        #pragma unroll
        for (int q = 0; q < 4; ++q) {
            float4 a = Ah[q];
            acc += a.x * inter[q * 4 + 0] + a.y * inter[q * 4 + 1]
                 + a.z * inter[q * 4 + 2] + a.w * inter[q * 4 + 3];
        }
        op[j] += acc;
    }
    ((float4*)(out + (size_t)n * HID))[tid] = o;
}

extern "C" void kernel_launch(void* const* d_in, const int* in_sizes, int n_in,
                              void* d_out, int out_size, void* d_ws, size_t ws_size,
                              hipStream_t stream) {
    const float* x    = (const float*)d_in[0];
    const int*   seg  = (const int*)d_in[1];
    const float* A    = (const float*)d_in[2];
    const float* B    = (const float*)d_in[3];
    const float* bias = (const float*)d_in[4];
    float* out = (float*)d_out;

    const int n_tokens = in_sizes[1];  // segment_ids count == N

    lora_seg_kernel<<<n_tokens, 256, 0, stream>>>(x, seg, A, B, bias, out);
}

// Round 2
// 137.709 us; speedup vs baseline: 1.4284x; 1.4284x over previous
//
#include <hip/hip_runtime.h>
#include <hip/hip_bf16.h>

#define HID 1024
#define RANK 16
#define NSEG 64
#define NCHUNK 8

__global__ __launch_bounds__(256) void lora_grouped(
    const float* __restrict__ x,      // [N, H]
    const int*   __restrict__ seg,    // [N]
    const float* __restrict__ A,      // [S, H, R]
    const float* __restrict__ B,      // [S, R, H]
    const float* __restrict__ bias,   // [S, H]
    float*       __restrict__ out,    // [N, H]
    int N)
{
    const int bid  = blockIdx.x;
    const int s    = bid >> 3;        // segment
    const int c    = bid & (NCHUNK - 1);
    const int tid  = threadIdx.x;
    const int lane = tid & 63;
    const int wave = tid >> 6;

    __shared__ int   list[1024];
    __shared__ int   cnt;
    __shared__ float inter_lds[4][RANK];

    if (tid == 0) cnt = 0;
    __syncthreads();

    // ---- scan this block's token slice for segment matches ----
    const int chunkN = (N + NCHUNK - 1) / NCHUNK;
    const int i0 = c * chunkN;
    const int i1 = min(N, i0 + chunkN);
    for (int i = i0 + tid; i < i1; i += 256) {
        if (seg[i] == s) {
            int p = atomicAdd(&cnt, 1);
            if (p < 1024) list[p] = i;
        }
    }
    __syncthreads();
    const int m = min(cnt, 1024);
    if (m == 0) return;

    // ---- hoist A[s] into registers: thread owns h = tid*4 .. tid*4+3 ----
    const float4* A4 = (const float4*)(A + (size_t)s * HID * RANK);
    float4 av[4][4];                      // av[jh][q]: row h0+jh, r = 4q..4q+3
    #pragma unroll
    for (int jh = 0; jh < 4; ++jh)
        #pragma unroll
        for (int q = 0; q < 4; ++q)
            av[jh][q] = A4[(size_t)(tid * 4 + jh) * (RANK / 4) + q];
    const float4 bia = ((const float4*)(bias + (size_t)s * HID))[tid];

    const float4* B4 = (const float4*)(B + (size_t)s * RANK * HID);

    // ---- process tokens in groups of 4 ----
    for (int t = 0; t < m; t += 4) {
        const int nt = min(4, m - t);
        int n[4];
        #pragma unroll
        for (int j = 0; j < 4; ++j)
            n[j] = list[t + (j < nt ? j : nt - 1)];

        // Phase 1: inter[j][r] = sum_h B[s][r][h] * x[n[j]][h]
        // wave owns r = wave*4 .. wave*4+3 ; lane covers h = lane*16..+15
        float4 xv[4][4];
        #pragma unroll
        for (int j = 0; j < 4; ++j) {
            const float4* xr = (const float4*)(x + (size_t)n[j] * HID);
            #pragma unroll
            for (int k = 0; k < 4; ++k) xv[j][k] = xr[lane * 4 + k];
        }

        float acc[4][4];                  // [rr][j]
        #pragma unroll
        for (int rr = 0; rr < 4; ++rr)
            #pragma unroll
            for (int j = 0; j < 4; ++j) acc[rr][j] = 0.f;

        #pragma unroll
        for (int rr = 0; rr < 4; ++rr) {
            const float4* Br = B4 + (size_t)(wave * 4 + rr) * (HID / 4);
            #pragma unroll
            for (int k = 0; k < 4; ++k) {
                float4 b = Br[lane * 4 + k];
                #pragma unroll
                for (int j = 0; j < 4; ++j)
                    acc[rr][j] += b.x * xv[j][k].x + b.y * xv[j][k].y
                                + b.z * xv[j][k].z + b.w * xv[j][k].w;
            }
        }

        #pragma unroll
        for (int rr = 0; rr < 4; ++rr)
            #pragma unroll
            for (int j = 0; j < 4; ++j) {
                float v = acc[rr][j];
                #pragma unroll
                for (int off = 32; off >= 1; off >>= 1)
                    v += __shfl_xor(v, off, 64);
                if (lane == 0) inter_lds[j][wave * 4 + rr] = v;
            }
        __syncthreads();

        // Phase 2: out[n[j]][h] = sum_r A[s][h][r]*inter[j][r] + bias[s][h]
        #pragma unroll
        for (int j = 0; j < 4; ++j) {
            const float4* I4 = (const float4*)inter_lds[j];
            float4 iv[4];
            #pragma unroll
            for (int q = 0; q < 4; ++q) iv[q] = I4[q];
            float4 o = bia;
            float* op = (float*)&o;
            #pragma unroll
            for (int jh = 0; jh < 4; ++jh) {
                float a = 0.f;
                #pragma unroll
                for (int q = 0; q < 4; ++q)
                    a += av[jh][q].x * iv[q].x + av[jh][q].y * iv[q].y
                       + av[jh][q].z * iv[q].z + av[jh][q].w * iv[q].w;
                op[jh] += a;
            }
            if (j < nt)
                ((float4*)(out + (size_t)n[j] * HID))[tid] = o;
        }
        __syncthreads();
    }
}

extern "C" void kernel_launch(void* const* d_in, const int* in_sizes, int n_in,
                              void* d_out, int out_size, void* d_ws, size_t ws_size,
                              hipStream_t stream) {
    const float* x    = (const float*)d_in[0];
    const int*   seg  = (const int*)d_in[1];
    const float* A    = (const float*)d_in[2];
    const float* B    = (const float*)d_in[3];
    const float* bias = (const float*)d_in[4];
    float* out = (float*)d_out;

    const int n_tokens = in_sizes[1];

    lora_grouped<<<NSEG * NCHUNK, 256, 0, stream>>>(x, seg, A, B, bias, out, n_tokens);
}